// Round 18
// baseline (587.289 us; speedup 1.0000x reference)
//
#include <hip/hip_runtime.h>
#include <hip/hip_bf16.h>

#define NTOK 16384
#define HID 7168
#define NEXP 256
#define TOPK 8
#define NCHK 14            // mega-chunks of 512 k
#define CSTEP 32           // 16-k steps per chunk
#define REP 2              // diagnostic repeat factor

typedef __bf16 bf16x8 __attribute__((ext_vector_type(8)));
typedef float  f32x16 __attribute__((ext_vector_type(16)));

// Weights, MFMA-fragment-linear (R12-proven layout):
// uint4 idx = ((p8*8 + g)*8 + ks)*64 + lane holds
// B[e = g*32 + (lane&31)][k = p8*128 + ks*16 + (lane>>5)*8 .. +8]
__device__ __align__(16) unsigned short g_wb[NEXP * HID];

__device__ __forceinline__ unsigned int f2bfb(float x) {
    unsigned int u = __float_as_uint(x);
    return (u + 0x7fffu + ((u >> 16) & 1u)) >> 16;
}
__device__ __forceinline__ uint4 pk4(float4 p, float4 q) {
    uint4 u;
    u.x = f2bfb(p.x) | (f2bfb(p.y) << 16);
    u.y = f2bfb(p.z) | (f2bfb(p.w) << 16);
    u.z = f2bfb(q.x) | (f2bfb(q.y) << 16);
    u.w = f2bfb(q.z) | (f2bfb(q.w) << 16);
    return u;
}
__device__ __forceinline__ bf16x8 asbf8(uint4 u) {
    union { uint4 a; bf16x8 b; } c; c.a = u; return c.b;
}

__global__ void wconv_frag(const float* __restrict__ wt) {
    const int tid = blockIdx.x * 256 + threadIdx.x;
    const int l  = tid & 63;
    const int ks = (tid >> 6) & 7;
    const int g  = (tid >> 9) & 7;
    const int p  = tid >> 12;
    const int e  = g * 32 + (l & 31);
    const int kb = p * 128 + ks * 16 + ((l >> 5) << 3);
    const float4* s = (const float4*)(wt + (size_t)e * HID + kb);
    ((uint4*)g_wb)[tid] = pk4(s[0], s[1]);
}

__global__ void moe_rows(float* __restrict__ ob) {
    const int q = blockIdx.x * 256 + threadIdx.x;
    ob[262144 + q] = (float)((q & 7) * NTOK + (q >> 3));
}

// ---------------- shared index macros for the diagnostic trio ----------------
#define DIAG_PRELUDE                                                          \
    __shared__ __align__(16) char smem[33792];                                \
    const int tid   = threadIdx.x;                                            \
    const int lane  = tid & 63;                                               \
    const int w     = tid >> 6;                                               \
    const int khalf = lane >> 5;                                              \
    const int bid   = blockIdx.x;                                             \
    const int sb    = (bid & 7) * 64 + (bid >> 3);                            \
    const int t0    = sb * 32;                                                \
    const int boff  = bid % NCHK;                                             \
    const int srow = tid >> 4;                                                \
    const int ssub = tid & 15;                                                \
    const float* astage = hs + (size_t)(t0 + srow) * HID + ssub * 32;         \
    int adst[4];                                                              \
    _Pragma("unroll")                                                         \
    for (int d = 0; d < 4; ++d)                                               \
        adst[d] = srow * 1024 + (((ssub * 4 + d) ^ (srow & 7)) << 4);         \
    const int arow  = lane & 31;                                              \
    const int abase = arow * 1024;                                            \
    const int amask = arow & 7;                                               \
    const char* const bbase = (const char*)g_wb + w * 8192 + lane * 16;       \
    (void)khalf; (void)abase; (void)amask; (void)bbase; (void)astage;

#define STAGE_A(CC)                                                           \
    do {                                                                      \
        _Pragma("unroll")                                                     \
        for (int d = 0; d < 4; ++d) {                                         \
            float4 v0 = *(const float4*)(astage + (size_t)(CC) * 512 + d * 8);     \
            float4 v1 = *(const float4*)(astage + (size_t)(CC) * 512 + d * 8 + 4); \
            *(uint4*)(smem + adst[d]) = pk4(v0, v1);                          \
        }                                                                     \
    } while (0)

#define BADDR(J16) (bbase + (size_t)(((J16) >> 3) * 64 + ((J16) & 7)) * 1024)
#define LOADB(R, J16)                                                         \
    do { R = *(const uint4*)BADDR(J16); __builtin_amdgcn_sched_barrier(0); } while (0)
#define VMW(N)                                                                \
    do {                                                                      \
        asm volatile("s_waitcnt vmcnt(" #N ")" ::: "memory");                 \
        __builtin_amdgcn_sched_barrier(0);                                    \
    } while (0)
#define EAT(R) (R.x ^ R.y ^ R.z ^ R.w)
#define CMP(J, R)                                                             \
    do {                                                                      \
        const int off = ((((J) * 2 + khalf) ^ amask) << 4);                   \
        bf16x8 a = *(const bf16x8*)(smem + abase + off);                      \
        acc = __builtin_amdgcn_mfma_f32_32x32x16_bf16(a, asbf8(R), acc, 0, 0, 0); \
    } while (0)

// ---- DIAG 1: loads-only (A staging + depth-8 B pipeline + VMW; no MFMA) ----
__global__ __launch_bounds__(512, 4) void moe_diag_loads(
    const float* __restrict__ hs, unsigned int* __restrict__ out)
{
    DIAG_PRELUDE
    unsigned int chk = 0;
    uint4 b0, b1, b2, b3, b4, b5, b6, b7;
    for (int rep = 0; rep < REP; ++rep)
    for (int c = 0; c < NCHK; ++c) {
        int cc = c + boff; if (cc >= NCHK) cc -= NCHK;
        __syncthreads();
        STAGE_A(cc);
        __syncthreads();
        const int J0 = cc * CSTEP;
        LOADB(b0, J0 + 0); LOADB(b1, J0 + 1); LOADB(b2, J0 + 2); LOADB(b3, J0 + 3);
        LOADB(b4, J0 + 4); LOADB(b5, J0 + 5); LOADB(b6, J0 + 6); LOADB(b7, J0 + 7);
        #pragma unroll
        for (int jj = 0; jj < 3; ++jj) {
            const int j = jj * 8;
            VMW(7); chk ^= EAT(b0); LOADB(b0, J0 + j +  8);
            VMW(7); chk ^= EAT(b1); LOADB(b1, J0 + j +  9);
            VMW(7); chk ^= EAT(b2); LOADB(b2, J0 + j + 10);
            VMW(7); chk ^= EAT(b3); LOADB(b3, J0 + j + 11);
            VMW(7); chk ^= EAT(b4); LOADB(b4, J0 + j + 12);
            VMW(7); chk ^= EAT(b5); LOADB(b5, J0 + j + 13);
            VMW(7); chk ^= EAT(b6); LOADB(b6, J0 + j + 14);
            VMW(7); chk ^= EAT(b7); LOADB(b7, J0 + j + 15);
        }
        VMW(7); chk ^= EAT(b0);
        VMW(6); chk ^= EAT(b1);
        VMW(5); chk ^= EAT(b2);
        VMW(4); chk ^= EAT(b3);
        VMW(3); chk ^= EAT(b4);
        VMW(2); chk ^= EAT(b5);
        VMW(1); chk ^= EAT(b6);
        VMW(0); chk ^= EAT(b7);
    }
    out[(size_t)bid * 512 + tid] = chk;
}

// ---- DIAG 2: MFMA+LDS only (B fixed in regs; no loads in the loop) ----
__global__ __launch_bounds__(512, 4) void moe_diag_mfma(
    const float* __restrict__ hs, unsigned int* __restrict__ out)
{
    DIAG_PRELUDE
    f32x16 acc = {};
    uint4 b0, b1, b2, b3, b4, b5, b6, b7;
    LOADB(b0, 0); LOADB(b1, 1); LOADB(b2, 2); LOADB(b3, 3);
    LOADB(b4, 4); LOADB(b5, 5); LOADB(b6, 6); LOADB(b7, 7);
    VMW(0);
    for (int rep = 0; rep < REP; ++rep)
    for (int c = 0; c < NCHK; ++c) {
        int cc = c + boff; if (cc >= NCHK) cc -= NCHK;
        __syncthreads();
        STAGE_A(cc);
        __syncthreads();
        #pragma unroll
        for (int jj = 0; jj < 4; ++jj) {
            const int j = jj * 8;
            CMP(j + 0, b0); CMP(j + 1, b1); CMP(j + 2, b2); CMP(j + 3, b3);
            CMP(j + 4, b4); CMP(j + 5, b5); CMP(j + 6, b6); CMP(j + 7, b7);
        }
    }
    float s = 0.f;
    #pragma unroll
    for (int r = 0; r < 16; ++r) s += acc[r];
    out[(size_t)bid * 512 + tid] = __float_as_uint(s);
}

// ---- DIAG 3: bare scaffold (barriers + trivial VALU; no memory, no MFMA) ----
__global__ __launch_bounds__(512, 4) void moe_diag_empty(
    const float* __restrict__ hs, unsigned int* __restrict__ out)
{
    DIAG_PRELUDE
    unsigned int chk = tid;
    for (int rep = 0; rep < REP; ++rep)
    for (int c = 0; c < NCHK; ++c) {
        int cc = c + boff; if (cc >= NCHK) cc -= NCHK;
        __syncthreads();
        __syncthreads();
        #pragma unroll
        for (int j = 0; j < CSTEP; ++j) chk = chk * 5u + (unsigned)cc;
    }
    out[(size_t)bid * 512 + tid] = chk;
}

// ---- correctness carrier: R15 kernel verbatim (best passing, 243.6 us) ----
__global__ __launch_bounds__(512, 4) void moe_gate_v15(
    const float* __restrict__ hs,
    float* __restrict__ ob)
{
    __shared__ __align__(16) char smem[33792];

    const int tid   = threadIdx.x;
    const int lane  = tid & 63;
    const int w     = tid >> 6;
    const int khalf = lane >> 5;
    const int t0    = blockIdx.x * 32;

    const int ar = tid >> 4;
    const int ac = tid & 15;
    const float* aload = hs + (size_t)(t0 + ar) * HID + ac * 4;
    const int awb = (ac >> 1) * 512 + ar * 16 + (ac & 1) * 8;

    const int arb = (lane & 31) * 16;
    const char* const bbase = (const char*)g_wb + w * 8192 + lane * 16;

    f32x16 acc = {};
    uint4 bA0, bA1, bA2, bA3;
    uint4 bB0, bB1, bB2, bB3;

    char* p0 = smem;
    char* p1 = smem + 4096;
    char* p2 = smem + 8192;

#define LOADB15(SET, S)                                                       \
    do {                                                                      \
        const char* bp = bbase + (size_t)((S) >> 1) * 65536 + ((S) & 1) * 4096; \
        b##SET##0 = *(const uint4*)(bp);                                      \
        b##SET##1 = *(const uint4*)(bp + 1024);                               \
        b##SET##2 = *(const uint4*)(bp + 2048);                               \
        b##SET##3 = *(const uint4*)(bp + 3072);                               \
    } while (0)

#define WRITEA15(V, BUF)                                                      \
    do {                                                                      \
        uint2 u;                                                              \
        u.x = f2bfb((V).x) | (f2bfb((V).y) << 16);                            \
        u.y = f2bfb((V).z) | (f2bfb((V).w) << 16);                            \
        *(uint2*)((BUF) + awb) = u;                                           \
    } while (0)

#define COMPUTE15(BUF, SET)                                                   \
    do {                                                                      \
        bf16x8 a;                                                             \
        a = *(const bf16x8*)((BUF) + (0 * 2 + khalf) * 512 + arb);            \
        acc = __builtin_amdgcn_mfma_f32_32x32x16_bf16(a, asbf8(b##SET##0), acc, 0, 0, 0); \
        a = *(const bf16x8*)((BUF) + (1 * 2 + khalf) * 512 + arb);            \
        acc = __builtin_amdgcn_mfma_f32_32x32x16_bf16(a, asbf8(b##SET##1), acc, 0, 0, 0); \
        a = *(const bf16x8*)((BUF) + (2 * 2 + khalf) * 512 + arb);            \
        acc = __builtin_amdgcn_mfma_f32_32x32x16_bf16(a, asbf8(b##SET##2), acc, 0, 0, 0); \
        a = *(const bf16x8*)((BUF) + (3 * 2 + khalf) * 512 + arb);            \
        acc = __builtin_amdgcn_mfma_f32_32x32x16_bf16(a, asbf8(b##SET##3), acc, 0, 0, 0); \
    } while (0)

    {
        float4 v0 = *(const float4*)(aload);
        float4 v1 = *(const float4*)(aload + 64);
        WRITEA15(v0, p0);
        WRITEA15(v1, p1);
    }
    LOADB15(A, 0);
    __syncthreads();

    for (int s = 0; s < 112; s += 2) {
        float4 vA;
        const bool ldA = (s + 2 < 112);
        if (ldA) vA = *(const float4*)(aload + (size_t)(s + 2) * 64);
        LOADB15(B, s + 1);
        COMPUTE15(p0, A);
        __syncthreads();
        if (ldA) WRITEA15(vA, p2);

        float4 vB;
        const bool ldB = (s + 3 < 112);
        if (ldB) vB = *(const float4*)(aload + (size_t)(s + 3) * 64);
        if (s + 2 < 112) LOADB15(A, s + 2);
        COMPUTE15(p1, B);
        __syncthreads();
        if (ldB) WRITEA15(vB, p0);

        char* t = p2; p2 = p1; p1 = p0; p0 = t;
    }

    float* ll = (float*)smem;
    {
        const int ec = w * 32 + (lane & 31);
        #pragma unroll
        for (int r = 0; r < 16; ++r) {
            const int tok = (r & 3) + 8 * (r >> 2) + 4 * khalf;
            ll[tok * 257 + ec] = acc[r];
        }
    }
    __syncthreads();

    if (tid < 32) {
        const float* lr = ll + tid * 257;
        float bv[TOPK]; int bi8[TOPK];
        #pragma unroll
        for (int k = 0; k < TOPK; ++k) { bv[k] = -1e30f; bi8[k] = 0; }
        for (int e = 0; e < NEXP; ++e) {
            const float v = lr[e];
            if (v > bv[TOPK - 1]) {
                int k = TOPK - 1;
                while (k > 0 && v > bv[k - 1]) {
                    bv[k] = bv[k - 1]; bi8[k] = bi8[k - 1]; --k;
                }
                bv[k] = v; bi8[k] = e;
            }
        }
        float ev[TOPK], ssum = 0.f;
        #pragma unroll
        for (int r = 0; r < TOPK; ++r) { ev[r] = expf(bv[r] - bv[0]); ssum += ev[r]; }
        const float inv = 1.0f / ssum;

        const int tg = t0 + tid;
        #pragma unroll
        for (int r = 0; r < TOPK; ++r) {
            ob[(size_t)tg * TOPK + r]          = (float)bi8[r];
            ob[131072 + (size_t)tg * TOPK + r] = ev[r] * inv;
        }
    }
#undef LOADB15
#undef WRITEA15
#undef COMPUTE15
}

extern "C" void kernel_launch(void* const* d_in, const int* in_sizes, int n_in,
                              void* d_out, int out_size, void* d_ws, size_t ws_size,
                              hipStream_t stream) {
    const float* hs = (const float*)d_in[0];   // [16384, 7168] f32
    const float* wt = (const float*)d_in[1];   // [256, 7168] f32
    float* ob = (float*)d_out;                 // f32[393216]: idx | weight | row
    unsigned int* ws = (unsigned int*)d_ws;    // diag checksums (3 MB used)

    wconv_frag<<<dim3(NEXP * HID / 8 / 256), dim3(256), 0, stream>>>(wt);
    moe_diag_loads<<<dim3(512), dim3(512), 0, stream>>>(hs, ws);
    moe_diag_mfma <<<dim3(512), dim3(512), 0, stream>>>(hs, ws + 262144);
    moe_diag_empty<<<dim3(512), dim3(512), 0, stream>>>(hs, ws + 524288);
    moe_gate_v15  <<<dim3(NTOK / 32), dim3(512), 0, stream>>>(hs, ob);
    moe_rows      <<<dim3(512), dim3(256), 0, stream>>>(ob);
}

// Round 19
// 416.586 us; speedup vs baseline: 1.4098x; 1.4098x over previous
//
#include <hip/hip_runtime.h>
#include <hip/hip_bf16.h>

#define NTOK 16384
#define HID 7168
#define NEXP 256
#define TOPK 8

typedef __bf16 bf16x8 __attribute__((ext_vector_type(8)));
typedef float  f32x16 __attribute__((ext_vector_type(16)));
typedef __attribute__((address_space(1))) const unsigned char ga_t;
typedef __attribute__((address_space(3))) unsigned char la_t;

// Weights, MFMA-fragment-linear (R12-proven):
// byte = p8*65536 + g*8192 + ks*1024 + lane*16 holds
// B[e = g*32 + (lane&31)][k = p8*128 + ks*16 + (lane>>5)*8 .. +8]
__device__ __align__(16) unsigned short g_wb[NEXP * HID];

__device__ __forceinline__ unsigned int f2bfb(float x) {
    unsigned int u = __float_as_uint(x);
    return (u + 0x7fffu + ((u >> 16) & 1u)) >> 16;
}
__device__ __forceinline__ uint4 pk4(float4 p, float4 q) {
    uint4 u;
    u.x = f2bfb(p.x) | (f2bfb(p.y) << 16);
    u.y = f2bfb(p.z) | (f2bfb(p.w) << 16);
    u.z = f2bfb(q.x) | (f2bfb(q.y) << 16);
    u.w = f2bfb(q.z) | (f2bfb(q.w) << 16);
    return u;
}
__device__ __forceinline__ void gll16(const void* g, void* l) {
    __builtin_amdgcn_global_load_lds((ga_t*)g, (la_t*)l, 16, 0, 0);
}

__global__ void wconv_frag(const float* __restrict__ wt) {
    const int tid = blockIdx.x * 256 + threadIdx.x;
    const int l  = tid & 63;
    const int ks = (tid >> 6) & 7;
    const int g  = (tid >> 9) & 7;
    const int p  = tid >> 12;
    const int e  = g * 32 + (l & 31);
    const int kb = p * 128 + ks * 16 + ((l >> 5) << 3);
    const float4* s = (const float4*)(wt + (size_t)e * HID + kb);
    ((uint4*)g_wb)[tid] = pk4(s[0], s[1]);
}

__global__ void moe_rows(float* __restrict__ ob) {
    const int q = blockIdx.x * 256 + threadIdx.x;
    ob[262144 + q] = (float)((q & 7) * NTOK + (q >> 3));
}

// ---- gate: grid (64, KS); block 512 thr = 8 waves (2 tok-half x 4 exp-qtr).
// Block tile 256 tok x 256 exp x KLEN. Wave 128x64: acc[4][2] f32x16.
// A: reg->cvt->swizzled LDS dbuf (2x32KB). B: gll from g_wb dbuf (2x32KB).
template<int KS>
__global__ __launch_bounds__(512, 1) void moe_gate_v19(
    const float* __restrict__ hs,
    float* __restrict__ pw)
{
    constexpr int KLEN  = HID / KS;
    constexpr int NSTEP = KLEN / 64;
    __shared__ __align__(16) char smem[131072];
    char* const bA0 = smem;
    char* const bA1 = smem + 32768;
    char* const bB0 = smem + 65536;
    char* const bB1 = smem + 98304;

    const int tid   = threadIdx.x;
    const int lane  = tid & 63;
    const int l31   = lane & 31;
    const int khalf = lane >> 5;
    const int wv    = tid >> 6;       // 0..7
    const int wm    = wv >> 2;        // tok half
    const int wn    = wv & 3;         // exp quarter
    const int t0    = blockIdx.x * 256;
    const int by    = blockIdx.y;

    // A stage: thread -> (row r = tid>>1, half h = tid&1, 32 f32)
    const int r = tid >> 1;
    const int h = tid & 1;
    const float* aptr = hs + (size_t)(t0 + r) * HID + by * KLEN + h * 32;
    int awb[4];
    #pragma unroll
    for (int j = 0; j < 4; ++j)
        awb[j] = r * 128 + ((h * 64 + j * 16) ^ ((r & 7) << 4));

    // B gll source base (fragment-linear)
    const char* const bsrc0 = (const char*)g_wb
        + ((size_t)by * (KLEN / 128)) * 65536 + wv * 8192 + lane * 16;
    const int bdst = wv * 4096;

    // fragment read addresses
    int arowb[4];
    #pragma unroll
    for (int mi = 0; mi < 4; ++mi)
        arowb[mi] = (wm * 128 + mi * 32 + l31) * 128;
    int offk[4];
    #pragma unroll
    for (int kk = 0; kk < 4; ++kk)
        offk[kk] = (kk * 32 + khalf * 16) ^ ((l31 & 7) << 4);

    f32x16 acc[4][2] = {};
    float4 fa[8];

#define LOADA(S)                                                              \
    do {                                                                      \
        _Pragma("unroll")                                                     \
        for (int j = 0; j < 8; ++j)                                           \
            fa[j] = *(const float4*)(aptr + (size_t)(S) * 64 + j * 4);        \
        __builtin_amdgcn_sched_barrier(0);                                    \
    } while (0)

#define ISSUEB(S, BUF)                                                       \
    do {                                                                      \
        const char* sp = bsrc0 + ((size_t)((S) >> 1)) * 65536 + ((S) & 1) * 4096; \
        _Pragma("unroll")                                                     \
        for (int q = 0; q < 4; ++q)                                           \
            gll16(sp + q * 1024, (BUF) + bdst + q * 1024);                    \
        __builtin_amdgcn_sched_barrier(0);                                    \
    } while (0)

#define CVTWRITE(BUF)                                                        \
    do {                                                                      \
        _Pragma("unroll")                                                     \
        for (int j = 0; j < 4; ++j)                                           \
            *(uint4*)((BUF) + awb[j]) = pk4(fa[2 * j], fa[2 * j + 1]);        \
    } while (0)

#define COMPUTE(BA, BB)                                                      \
    do {                                                                      \
        _Pragma("unroll")                                                     \
        for (int kk = 0; kk < 4; ++kk) {                                      \
            bf16x8 av[4], bv[2];                                              \
            _Pragma("unroll")                                                 \
            for (int mi = 0; mi < 4; ++mi)                                    \
                av[mi] = *(const bf16x8*)((BA) + arowb[mi] + offk[kk]);       \
            _Pragma("unroll")                                                 \
            for (int n = 0; n < 2; ++n)                                       \
                bv[n] = *(const bf16x8*)((BB) + (2 * wn + n) * 4096 + kk * 1024 + lane * 16); \
            _Pragma("unroll")                                                 \
            for (int mi = 0; mi < 4; ++mi)                                    \
                _Pragma("unroll")                                             \
                for (int n = 0; n < 2; ++n)                                   \
                    acc[mi][n] = __builtin_amdgcn_mfma_f32_32x32x16_bf16(     \
                        av[mi], bv[n], acc[mi][n], 0, 0, 0);                  \
        }                                                                     \
    } while (0)

#define VMWB(N)                                                              \
    do {                                                                      \
        asm volatile("s_waitcnt vmcnt(" #N ")" ::: "memory");                 \
        __builtin_amdgcn_sched_barrier(0);                                    \
        asm volatile("s_barrier" ::: "memory");                               \
        __builtin_amdgcn_sched_barrier(0);                                    \
    } while (0)

#define LGKB()                                                               \
    do {                                                                      \
        asm volatile("s_waitcnt lgkmcnt(0)\n\ts_barrier" ::: "memory");       \
        __builtin_amdgcn_sched_barrier(0);                                    \
    } while (0)

    // ---- prologue: A(0)->regs->bA0, B(0) gll -> bB0 ----
    LOADA(0);
    ISSUEB(0, bB0);
    CVTWRITE(bA0);                 // compiler waits A(0) regs (B(0) younger, stays)
    LGKB();                        // FIFO: [B(0) x4]

    // ---- main loop (x2 unrolled, template cadence) ----
    for (int s = 0; s < NSTEP; s += 2) {
        // even step s: compute bA0/bB0
        LOADA(s + 1);
        ISSUEB(s + 1, bB1);        // FIFO: [B(s)4, A8, B(s+1)4]
        VMWB(12);                  // B(s) landed (all waves)
        COMPUTE(bA0, bB0);
        CVTWRITE(bA1);             // compiler vmcnt(4): A regs done, B(s+1) in flight
        LGKB();

        if (s + 2 < NSTEP) {
            // odd step s+1: compute bA1/bB1
            LOADA(s + 2);
            ISSUEB(s + 2, bB0);
            VMWB(12);
            COMPUTE(bA1, bB1);
            CVTWRITE(bA0);
            LGKB();
        } else {
            VMWB(0);               // drain B(NSTEP-1)
            COMPUTE(bA1, bB1);
        }
    }

    // ---- epilogue: partial logits -> workspace ----
    float* const base = pw + ((size_t)by * NTOK + t0) * 256;
    #pragma unroll
    for (int mi = 0; mi < 4; ++mi)
        #pragma unroll
        for (int n = 0; n < 2; ++n)
            #pragma unroll
            for (int rr = 0; rr < 16; ++rr) {
                const int tokl = wm * 128 + mi * 32 + (rr & 3) + 8 * (rr >> 2) + 4 * khalf;
                const int ec   = wn * 64 + n * 32 + l31;
                base[(size_t)tokl * 256 + ec] = acc[mi][n][rr];
            }
#undef LOADA
#undef ISSUEB
#undef CVTWRITE
#undef COMPUTE
#undef VMWB
#undef LGKB
}

// ---- reduce: sum KS planes, top-8 + renormalized softmax (R14-proven) ----
template<int KS>
__global__ __launch_bounds__(256) void moe_reduce(
    const float* __restrict__ pw,
    float* __restrict__ ob)
{
    __shared__ float ll[64 * 257];
    const int tid = threadIdx.x;
    const size_t ro = (size_t)blockIdx.x * 16384;        // 64 tok x 256 exp
    const size_t PS = (size_t)NTOK * 256;

    #pragma unroll
    for (int j = 0; j < 16; ++j) {
        const size_t f = (size_t)j * 1024 + tid * 4;
        float4 v = *(const float4*)(pw + ro + f);
        #pragma unroll
        for (int s = 1; s < KS; ++s) {
            float4 u = *(const float4*)(pw + s * PS + ro + f);
            v.x += u.x; v.y += u.y; v.z += u.z; v.w += u.w;
        }
        const int t = (int)(f >> 8);
        const int e = (int)(f & 255);
        *(float4*)&ll[t * 257 + e] = v;
    }
    __syncthreads();

    if (tid < 64) {
        const float* lr = ll + tid * 257;
        float bv[TOPK]; int bi8[TOPK];
        #pragma unroll
        for (int k = 0; k < TOPK; ++k) { bv[k] = -1e30f; bi8[k] = 0; }
        for (int e = 0; e < NEXP; ++e) {
            const float v = lr[e];
            if (v > bv[TOPK - 1]) {
                int k = TOPK - 1;
                while (k > 0 && v > bv[k - 1]) {
                    bv[k] = bv[k - 1]; bi8[k] = bi8[k - 1]; --k;
                }
                bv[k] = v; bi8[k] = e;      // strict > : ties keep lower idx
            }
        }
        float ev[TOPK], ssum = 0.f;
        #pragma unroll
        for (int rr = 0; rr < TOPK; ++rr) { ev[rr] = expf(bv[rr] - bv[0]); ssum += ev[rr]; }
        const float inv = 1.0f / ssum;

        const int tg = blockIdx.x * 64 + tid;
        #pragma unroll
        for (int rr = 0; rr < TOPK; ++rr) {
            ob[(size_t)tg * TOPK + rr]          = (float)bi8[rr];   // idx
            ob[131072 + (size_t)tg * TOPK + rr] = ev[rr] * inv;     // weight
        }
    }
}

extern "C" void kernel_launch(void* const* d_in, const int* in_sizes, int n_in,
                              void* d_out, int out_size, void* d_ws, size_t ws_size,
                              hipStream_t stream) {
    const float* hs = (const float*)d_in[0];   // [16384, 7168] f32
    const float* wt = (const float*)d_in[1];   // [256, 7168] f32
    float* ob = (float*)d_out;                 // f32[393216]: idx | weight | row
    float* pw = (float*)d_ws;

    wconv_frag<<<dim3(NEXP * HID / 8 / 256), dim3(256), 0, stream>>>(wt);

    const size_t need4 = (size_t)4 * NTOK * NEXP * sizeof(float);   // 64 MB
    if (ws_size >= need4) {
        moe_gate_v19<4><<<dim3(64, 4), dim3(512), 0, stream>>>(hs, pw);
        moe_reduce<4><<<dim3(256), dim3(256), 0, stream>>>(pw, ob);
    } else {
        moe_gate_v19<1><<<dim3(64, 1), dim3(512), 0, stream>>>(hs, pw);
        moe_reduce<1><<<dim3(256), dim3(256), 0, stream>>>(pw, ob);
    }
    moe_rows<<<dim3(512), dim3(256), 0, stream>>>(ob);
}

// Round 20
// 315.306 us; speedup vs baseline: 1.8626x; 1.3212x over previous
//
#include <hip/hip_runtime.h>
#include <hip/hip_bf16.h>

#define NTOK 16384
#define HID 7168
#define NEXP 256
#define TOPK 8

typedef __bf16 bf16x8 __attribute__((ext_vector_type(8)));
typedef float  f32x16 __attribute__((ext_vector_type(16)));

// Weights, MFMA-fragment-linear (R12-proven, absmax-251-stable):
// byte = p8*65536 + g*8192 + ks*1024 + lane*16 holds
// B[e = g*32 + (lane&31)][k = p8*128 + ks*16 + (lane>>5)*8 .. +8]
__device__ __align__(16) unsigned short g_wb[NEXP * HID];

__device__ __forceinline__ unsigned int f2bfb(float x) {
    unsigned int u = __float_as_uint(x);
    return (u + 0x7fffu + ((u >> 16) & 1u)) >> 16;
}
__device__ __forceinline__ uint4 pk4(float4 p, float4 q) {
    uint4 u;
    u.x = f2bfb(p.x) | (f2bfb(p.y) << 16);
    u.y = f2bfb(p.z) | (f2bfb(p.w) << 16);
    u.z = f2bfb(q.x) | (f2bfb(q.y) << 16);
    u.w = f2bfb(q.z) | (f2bfb(q.w) << 16);
    return u;
}
__device__ __forceinline__ bf16x8 asbf8(uint4 u) {
    union { uint4 a; bf16x8 b; } c; c.a = u; return c.b;
}

__global__ void wconv_frag(const float* __restrict__ wt) {
    const int tid = blockIdx.x * 256 + threadIdx.x;
    const int l  = tid & 63;
    const int ks = (tid >> 6) & 7;
    const int g  = (tid >> 9) & 7;
    const int p  = tid >> 12;
    const int e  = g * 32 + (l & 31);
    const int kb = p * 128 + ks * 16 + ((l >> 5) << 3);
    const float4* s = (const float4*)(wt + (size_t)e * HID + kb);
    ((uint4*)g_wb)[tid] = pk4(s[0], s[1]);
}

__global__ void moe_rows(float* __restrict__ ob) {
    const int q = blockIdx.x * 256 + threadIdx.x;
    ob[262144 + q] = (float)((q & 7) * NTOK + (q >> 3));
}

// ---- gate: grid (512, 2*KS); block 256 thr = 4 waves.
// by = kz*2 + ez: ez = expert half (128), kz = K slice (HID/KS).
// Wave w: experts ez*128 + w*32 .. +32; 32 tokens; v15 cadence.
// LDS: A bf16 dbuf 2 x 4 KB. B: fragment-linear g_wb -> regs (single set).
template<int KS>
__global__ __launch_bounds__(256, 6) void moe_gate_v20(
    const float* __restrict__ hs,
    float* __restrict__ pw)
{
    constexpr int KLEN  = HID / KS;
    constexpr int NSTEP = KLEN / 64;
    __shared__ __align__(16) char smem[8192];

    const int tid   = threadIdx.x;
    const int lane  = tid & 63;
    const int l31   = lane & 31;
    const int khalf = lane >> 5;
    const int w     = tid >> 6;          // 0..3
    const int t0    = blockIdx.x * 32;
    const int ez    = blockIdx.y & 1;
    const int kz    = blockIdx.y >> 1;

    // ---- A staging: thread -> (row tid>>3, 16-B k-chunk tid&7) ----
    const int ar = tid >> 3;             // 0..31
    const int akc = tid & 7;             // 0..7
    const float* aptr = hs + (size_t)(t0 + ar) * HID + kz * KLEN + akc * 8;
    const int awb = ar * 128 + ((akc ^ (ar & 7)) << 4);

    // ---- A fragment read: row l31, chunk (j*2+khalf)^ (row&7) ----
    const int arbase = l31 * 128;
    const int armask = l31 & 7;

    // ---- B fragment-linear base: group g = ez*4 + w ----
    const char* const bbase = (const char*)g_wb + (ez * 4 + w) * 8192 + lane * 16;

    f32x16 acc = {};
    float4 fa0, fa1;
    uint4 b0, b1, b2, b3;

#define LOADA(S)                                                              \
    do {                                                                      \
        fa0 = *(const float4*)(aptr + (size_t)(S) * 64);                      \
        fa1 = *(const float4*)(aptr + (size_t)(S) * 64 + 4);                  \
    } while (0)

#define WRITEA(BUF)                                                           \
    do { *(uint4*)((BUF) + awb) = pk4(fa0, fa1); } while (0)

#define LOADB(S)                                                              \
    do {                                                                      \
        const char* sp = bbase + (size_t)(kz * (KLEN / 128) + ((S) >> 1)) * 65536 \
                       + ((S) & 1) * 4096;                                    \
        b0 = *(const uint4*)(sp);                                             \
        b1 = *(const uint4*)(sp + 1024);                                      \
        b2 = *(const uint4*)(sp + 2048);                                      \
        b3 = *(const uint4*)(sp + 3072);                                      \
    } while (0)

#define COMPUTE(BUF)                                                          \
    do {                                                                      \
        bf16x8 a;                                                             \
        a = *(const bf16x8*)((BUF) + arbase + (((0 * 2 + khalf) ^ armask) << 4)); \
        acc = __builtin_amdgcn_mfma_f32_32x32x16_bf16(a, asbf8(b0), acc, 0, 0, 0); \
        a = *(const bf16x8*)((BUF) + arbase + (((1 * 2 + khalf) ^ armask) << 4)); \
        acc = __builtin_amdgcn_mfma_f32_32x32x16_bf16(a, asbf8(b1), acc, 0, 0, 0); \
        a = *(const bf16x8*)((BUF) + arbase + (((2 * 2 + khalf) ^ armask) << 4)); \
        acc = __builtin_amdgcn_mfma_f32_32x32x16_bf16(a, asbf8(b2), acc, 0, 0, 0); \
        a = *(const bf16x8*)((BUF) + arbase + (((3 * 2 + khalf) ^ armask) << 4)); \
        acc = __builtin_amdgcn_mfma_f32_32x32x16_bf16(a, asbf8(b3), acc, 0, 0, 0); \
    } while (0)

    char* cur = smem;
    char* oth = smem + 4096;

    // ---- prologue ----
    LOADA(0); LOADB(0);
    WRITEA(cur);                  // waits A(0) regs
    __syncthreads();

    // ---- main loop: v15 cadence, 1 sync/iter ----
    for (int s = 0; s < NSTEP; ++s) {
        const bool more = (s + 1 < NSTEP);
        if (more) LOADA(s + 1);
        COMPUTE(cur);             // waits b0..b3 (loaded prev iter)
        if (more) {
            LOADB(s + 1);         // issue after MFMA; lands across barrier
            WRITEA(oth);          // waits A(s+1) regs
            __syncthreads();
        }
        char* t = cur; cur = oth; oth = t;
    }

    // ---- epilogue: partial logits -> workspace (coalesced rows of 128 B) ----
    #pragma unroll
    for (int r = 0; r < 16; ++r) {
        const int tok = (r & 3) + 8 * (r >> 2) + 4 * khalf;
        pw[((size_t)kz * NTOK + t0 + tok) * 256 + ez * 128 + w * 32 + l31] = acc[r];
    }
#undef LOADA
#undef WRITEA
#undef LOADB
#undef COMPUTE
}

// ---- reduce: sum KS planes, top-8 + renormalized softmax (R14-proven) ----
template<int KS>
__global__ __launch_bounds__(256) void moe_reduce(
    const float* __restrict__ pw,
    float* __restrict__ ob)
{
    __shared__ float ll[64 * 257];
    const int tid = threadIdx.x;
    const size_t ro = (size_t)blockIdx.x * 16384;        // 64 tok x 256 exp
    const size_t PS = (size_t)NTOK * 256;

    #pragma unroll
    for (int j = 0; j < 16; ++j) {
        const size_t f = (size_t)j * 1024 + tid * 4;
        float4 v = *(const float4*)(pw + ro + f);
        #pragma unroll
        for (int s = 1; s < KS; ++s) {
            float4 u = *(const float4*)(pw + s * PS + ro + f);
            v.x += u.x; v.y += u.y; v.z += u.z; v.w += u.w;
        }
        const int t = (int)(f >> 8);
        const int e = (int)(f & 255);
        *(float4*)&ll[t * 257 + e] = v;
    }
    __syncthreads();

    if (tid < 64) {
        const float* lr = ll + tid * 257;
        float bv[TOPK]; int bi8[TOPK];
        #pragma unroll
        for (int k = 0; k < TOPK; ++k) { bv[k] = -1e30f; bi8[k] = 0; }
        for (int e = 0; e < NEXP; ++e) {
            const float v = lr[e];
            if (v > bv[TOPK - 1]) {
                int k = TOPK - 1;
                while (k > 0 && v > bv[k - 1]) {
                    bv[k] = bv[k - 1]; bi8[k] = bi8[k - 1]; --k;
                }
                bv[k] = v; bi8[k] = e;      // strict > : ties keep lower idx
            }
        }
        float ev[TOPK], ssum = 0.f;
        #pragma unroll
        for (int rr = 0; rr < TOPK; ++rr) { ev[rr] = expf(bv[rr] - bv[0]); ssum += ev[rr]; }
        const float inv = 1.0f / ssum;

        const int tg = blockIdx.x * 64 + tid;
        #pragma unroll
        for (int rr = 0; rr < TOPK; ++rr) {
            ob[(size_t)tg * TOPK + rr]          = (float)bi8[rr];   // idx
            ob[131072 + (size_t)tg * TOPK + rr] = ev[rr] * inv;     // weight
        }
    }
}

extern "C" void kernel_launch(void* const* d_in, const int* in_sizes, int n_in,
                              void* d_out, int out_size, void* d_ws, size_t ws_size,
                              hipStream_t stream) {
    const float* hs = (const float*)d_in[0];   // [16384, 7168] f32
    const float* wt = (const float*)d_in[1];   // [256, 7168] f32
    float* ob = (float*)d_out;                 // f32[393216]: idx | weight | row
    float* pw = (float*)d_ws;

    wconv_frag<<<dim3(NEXP * HID / 8 / 256), dim3(256), 0, stream>>>(wt);

    const size_t need2 = (size_t)2 * NTOK * NEXP * sizeof(float);   // 33.6 MB
    if (ws_size >= need2) {
        moe_gate_v20<2><<<dim3(512, 4), dim3(256), 0, stream>>>(hs, pw);
        moe_reduce<2><<<dim3(256), dim3(256), 0, stream>>>(pw, ob);
    } else {
        moe_gate_v20<1><<<dim3(512, 2), dim3(256), 0, stream>>>(hs, pw);
        moe_reduce<1><<<dim3(256), dim3(256), 0, stream>>>(pw, ob);
    }
    moe_rows<<<dim3(512), dim3(256), 0, stream>>>(ob);
}

// Round 21
// 242.302 us; speedup vs baseline: 2.4238x; 1.3013x over previous
//
#include <hip/hip_runtime.h>
#include <hip/hip_bf16.h>

#define NTOK 16384
#define HID 7168
#define NEXP 256
#define TOPK 8

#define BT 32                  // tokens per block
#define NIT 112                // K iterations (BK=64)

typedef __bf16 bf16x8 __attribute__((ext_vector_type(8)));
typedef float  f32x16 __attribute__((ext_vector_type(16)));

// Weights, MFMA-fragment-linear (R12-proven layout):
// uint4 idx = ((p8*8 + g)*8 + ks)*64 + lane holds
// B[e = g*32 + (lane&31)][k = p8*128 + ks*16 + (lane>>5)*8 .. +8]
__device__ __align__(16) unsigned short g_wb[NEXP * HID];

__device__ __forceinline__ unsigned int f2bfb(float x) {
    unsigned int u = __float_as_uint(x);
    return (u + 0x7fffu + ((u >> 16) & 1u)) >> 16;
}
__device__ __forceinline__ uint4 pk4(float4 p, float4 q) {
    uint4 u;
    u.x = f2bfb(p.x) | (f2bfb(p.y) << 16);
    u.y = f2bfb(p.z) | (f2bfb(p.w) << 16);
    u.z = f2bfb(q.x) | (f2bfb(q.y) << 16);
    u.w = f2bfb(q.z) | (f2bfb(q.w) << 16);
    return u;
}
__device__ __forceinline__ bf16x8 asbf8(uint4 u) {
    union { uint4 a; bf16x8 b; } c; c.a = u; return c.b;
}

__global__ void wconv_frag(const float* __restrict__ wt) {
    const int tid = blockIdx.x * 256 + threadIdx.x;
    const int l  = tid & 63;
    const int ks = (tid >> 6) & 7;
    const int g  = (tid >> 9) & 7;
    const int p  = tid >> 12;
    const int e  = g * 32 + (l & 31);
    const int kb = p * 128 + ks * 16 + ((l >> 5) << 3);
    const float4* s = (const float4*)(wt + (size_t)e * HID + kb);
    ((uint4*)g_wb)[tid] = pk4(s[0], s[1]);
}

__global__ void moe_rows(float* __restrict__ ob) {
    const int q = blockIdx.x * 256 + threadIdx.x;
    ob[262144 + q] = (float)((q & 7) * NTOK + (q >> 3));
}

// Block 512 thr = 8 waves; wave w: 32 tokens x experts [w*32, w*32+32).
// A: LDS bf16 tri-buffer 3 x 4 KB (async-split staging). B: regs from g_wb.
// LDS 33.8 KB; epilogue aliases logits [32][257] f32 over it.
__global__ __launch_bounds__(512, 4) void moe_gate_v15(
    const float* __restrict__ hs,
    float* __restrict__ ob)
{
    __shared__ __align__(16) char smem[33792];

    const int tid   = threadIdx.x;
    const int lane  = tid & 63;
    const int w     = tid >> 6;       // 0..7 = expert group
    const int khalf = lane >> 5;
    const int t0    = blockIdx.x * BT;

    // A staging: thread loads hs[t0 + (tid>>4)][s*64 + (tid&15)*4 .. +4]
    const int ar = tid >> 4;          // 0..31
    const int ac = tid & 15;          // 0..15
    const float* aload = hs + (size_t)(t0 + ar) * HID + ac * 4;
    const int awb = (ac >> 1) * 512 + ar * 16 + (ac & 1) * 8;   // bf16 dest byte

    // A fragment read: conflict-free contiguous (lanes 0..31 adjacent 16B)
    const int arb = (lane & 31) * 16;

    // B fragment-linear base for this wave's expert group
    const char* const bbase = (const char*)g_wb + w * 8192 + lane * 16;

    f32x16 acc = {};
    uint4 bA0, bA1, bA2, bA3;   // B set A
    uint4 bB0, bB1, bB2, bB3;   // B set B

    char* p0 = smem;            // read buf (iter s)
    char* p1 = smem + 4096;     // iter s+1
    char* p2 = smem + 8192;     // write target (iter s+2)

#define LOADB(SET, S)                                                         \
    do {                                                                      \
        const char* bp = bbase + (size_t)((S) >> 1) * 65536 + ((S) & 1) * 4096; \
        b##SET##0 = *(const uint4*)(bp);                                      \
        b##SET##1 = *(const uint4*)(bp + 1024);                               \
        b##SET##2 = *(const uint4*)(bp + 2048);                               \
        b##SET##3 = *(const uint4*)(bp + 3072);                               \
    } while (0)

#define WRITEA(V, BUF)                                                        \
    do {                                                                      \
        uint2 u;                                                              \
        u.x = f2bfb((V).x) | (f2bfb((V).y) << 16);                            \
        u.y = f2bfb((V).z) | (f2bfb((V).w) << 16);                            \
        *(uint2*)((BUF) + awb) = u;                                           \
    } while (0)

#define COMPUTE(BUF, SET)                                                     \
    do {                                                                      \
        bf16x8 a;                                                             \
        a = *(const bf16x8*)((BUF) + (0 * 2 + khalf) * 512 + arb);            \
        acc = __builtin_amdgcn_mfma_f32_32x32x16_bf16(a, asbf8(b##SET##0), acc, 0, 0, 0); \
        a = *(const bf16x8*)((BUF) + (1 * 2 + khalf) * 512 + arb);            \
        acc = __builtin_amdgcn_mfma_f32_32x32x16_bf16(a, asbf8(b##SET##1), acc, 0, 0, 0); \
        a = *(const bf16x8*)((BUF) + (2 * 2 + khalf) * 512 + arb);            \
        acc = __builtin_amdgcn_mfma_f32_32x32x16_bf16(a, asbf8(b##SET##2), acc, 0, 0, 0); \
        a = *(const bf16x8*)((BUF) + (3 * 2 + khalf) * 512 + arb);            \
        acc = __builtin_amdgcn_mfma_f32_32x32x16_bf16(a, asbf8(b##SET##3), acc, 0, 0, 0); \
    } while (0)

    // ---- prologue: A(0)->p0, A(1)->p1, B(0)->setA ----
    {
        float4 v0 = *(const float4*)(aload);
        float4 v1 = *(const float4*)(aload + 64);
        WRITEA(v0, p0);
        WRITEA(v1, p1);
    }
    LOADB(A, 0);
    __syncthreads();

    // ---- main loop: x2 unrolled; 1 sync/iter; A 2-ahead, B 1-ahead ----
    for (int s = 0; s < NIT; s += 2) {
        // iter s (read p0, set A)
        float4 vA;
        const bool ldA = (s + 2 < NIT);
        if (ldA) vA = *(const float4*)(aload + (size_t)(s + 2) * 64);
        LOADB(B, s + 1);
        COMPUTE(p0, A);
        __syncthreads();
        if (ldA) WRITEA(vA, p2);

        // iter s+1 (read p1, set B)
        float4 vB;
        const bool ldB = (s + 3 < NIT);
        if (ldB) vB = *(const float4*)(aload + (size_t)(s + 3) * 64);
        if (s + 2 < NIT) LOADB(A, s + 2);
        COMPUTE(p1, B);
        __syncthreads();
        if (ldB) WRITEA(vB, p0);

        // rotate: (p0,p1,p2) <- (p2,p0,p1)
        char* t = p2; p2 = p1; p1 = p0; p0 = t;
    }

    // ---- epilogue: logits [32][257] f32 aliased over smem ----
    float* ll = (float*)smem;
    {
        const int ec = w * 32 + (lane & 31);
        #pragma unroll
        for (int r = 0; r < 16; ++r) {
            const int tok = (r & 3) + 8 * (r >> 2) + 4 * khalf;
            ll[tok * 257 + ec] = acc[r];
        }
    }
    __syncthreads();

    if (tid < BT) {
        const float* lr = ll + tid * 257;
        float bv[TOPK]; int bi8[TOPK];
        #pragma unroll
        for (int k = 0; k < TOPK; ++k) { bv[k] = -1e30f; bi8[k] = 0; }
        for (int e = 0; e < NEXP; ++e) {
            const float v = lr[e];
            if (v > bv[TOPK - 1]) {
                int k = TOPK - 1;
                while (k > 0 && v > bv[k - 1]) {
                    bv[k] = bv[k - 1]; bi8[k] = bi8[k - 1]; --k;
                }
                bv[k] = v; bi8[k] = e;      // strict > : ties keep lower idx
            }
        }
        float ev[TOPK], ssum = 0.f;
        #pragma unroll
        for (int r = 0; r < TOPK; ++r) { ev[r] = expf(bv[r] - bv[0]); ssum += ev[r]; }
        const float inv = 1.0f / ssum;

        const int tg = t0 + tid;
        #pragma unroll
        for (int r = 0; r < TOPK; ++r) {
            ob[(size_t)tg * TOPK + r]          = (float)bi8[r];   // idx
            ob[131072 + (size_t)tg * TOPK + r] = ev[r] * inv;     // weight
        }
    }
#undef LOADB
#undef WRITEA
#undef COMPUTE
}

extern "C" void kernel_launch(void* const* d_in, const int* in_sizes, int n_in,
                              void* d_out, int out_size, void* d_ws, size_t ws_size,
                              hipStream_t stream) {
    const float* hs = (const float*)d_in[0];   // [16384, 7168] f32
    const float* wt = (const float*)d_in[1];   // [256, 7168] f32
    float* ob = (float*)d_out;                 // f32[393216]: idx | weight | row

    wconv_frag<<<dim3(NEXP * HID / 8 / 256), dim3(256), 0, stream>>>(wt);
    moe_gate_v15<<<dim3(NTOK / BT), dim3(512), 0, stream>>>(hs, ob);
    moe_rows<<<dim3(512), dim3(256), 0, stream>>>(ob);
}